// Round 7
// baseline (1769.737 us; speedup 1.0000x reference)
//
#include <hip/hip_runtime.h>
#include <hip/hip_bf16.h>

// Pipeline (fp32 throughout):
//  1. deg[i] = 1 + #in-edges  -> dis[i] = rsqrt(deg)
//  2. A = x @ W1; B[i,:] = dis[i]^2 * A[i,:]   (self-loop, fused in epilogue)
//  3. B += scatter_add(norm * A[src] -> dst) over real edges
//  4. A = relu(B + b1) @ W2; B = dis^2 * A     (fused; safe: each block reads
//     only its own B rows into LDS before overwriting them)
//  5. B += scatter_add(norm * A[src] -> dst)
//  6. Z[m] = mean over segment m of relu(B + b2)   (batch_idx sorted)
//  7. out = Z @ Wf + bf

#define GEMM_ROWS 32

__global__ __launch_bounds__(256)
void k_deg(const int* __restrict__ dst, float* __restrict__ deg, int E) {
    int i = blockIdx.x * blockDim.x + threadIdx.x;
    if (i < E) atomicAdd(&deg[dst[i]], 1.0f);
}

__global__ __launch_bounds__(256)
void k_dis(float* __restrict__ deg, int N) {
    int i = blockIdx.x * blockDim.x + threadIdx.x;
    if (i < N) deg[i] = rsqrtf(deg[i] + 1.0f);   // +1 self loop
}

// Y[r,:] = act(X[r,:]) @ W (+ bout), act = relu(x + bin) if RELU_IN.
// If SELF_INIT: also Binit[r,:] = dis[r]^2 * Y[r,:]  (self-loop contribution).
// W is 128x128 row-major; staged into LDS in two K=64 chunks (32KB) + X tile (16KB).
template<bool RELU_IN, bool OUT_BIAS, bool SELF_INIT>
__global__ __launch_bounds__(256)
void k_gemm128(const float* __restrict__ X, const float* __restrict__ W,
               const float* __restrict__ bin, const float* __restrict__ bout,
               float* __restrict__ Y, float* __restrict__ Binit,
               const float* __restrict__ dis, int nrows) {
    __shared__ float Ws[64 * 128];
    __shared__ float Xs[GEMM_ROWS * 128];
    const int tid = threadIdx.x;
    const int row0 = blockIdx.x * GEMM_ROWS;

    // stage X tile (with fused bias+relu on input)
    {
        float4* Xsv = (float4*)Xs;
        #pragma unroll
        for (int i = 0; i < 4; ++i) {
            int idx = tid + 256 * i;        // float4 index; 32 float4 per row
            int r   = idx >> 5;
            int c4  = idx & 31;
            int gr  = row0 + r;
            float4 v = {0.f, 0.f, 0.f, 0.f};
            if (gr < nrows) v = *(const float4*)&X[(size_t)gr * 128 + c4 * 4];
            if (RELU_IN) {
                float4 b = *(const float4*)&bin[c4 * 4];
                v.x = fmaxf(v.x + b.x, 0.f);
                v.y = fmaxf(v.y + b.y, 0.f);
                v.z = fmaxf(v.z + b.z, 0.f);
                v.w = fmaxf(v.w + b.w, 0.f);
            }
            Xsv[idx] = v;
        }
    }

    const int tx = tid & 31;    // col group: cols 4*tx..4*tx+3
    const int ty = tid >> 5;    // rows ty + 8*r, r=0..3
    float4 acc[4];
    #pragma unroll
    for (int r = 0; r < 4; ++r) acc[r] = {0.f, 0.f, 0.f, 0.f};

    for (int kk = 0; kk < 128; kk += 64) {
        __syncthreads();        // Xs ready (first iter) / Ws reuse safe (second)
        // stage W chunk [kk..kk+64) x 128 : 8192 floats = 2048 float4
        const float4* Wv = (const float4*)(W + kk * 128);
        float4* Wsv = (float4*)Ws;
        #pragma unroll
        for (int i = 0; i < 8; ++i) Wsv[tid + 256 * i] = Wv[tid + 256 * i];
        __syncthreads();

        #pragma unroll 4
        for (int k = 0; k < 64; ++k) {
            float4 w = *(const float4*)&Ws[k * 128 + tx * 4];
            #pragma unroll
            for (int r = 0; r < 4; ++r) {
                float xv = Xs[(ty + 8 * r) * 128 + kk + k];
                acc[r].x += xv * w.x;
                acc[r].y += xv * w.y;
                acc[r].z += xv * w.z;
                acc[r].w += xv * w.w;
            }
        }
    }

    #pragma unroll
    for (int r = 0; r < 4; ++r) {
        int gr = row0 + ty + 8 * r;
        if (gr < nrows) {
            float4 o = acc[r];
            if (OUT_BIAS) {
                float4 b = *(const float4*)&bout[tx * 4];
                o.x += b.x; o.y += b.y; o.z += b.z; o.w += b.w;
            }
            *(float4*)&Y[(size_t)gr * 128 + tx * 4] = o;
            if (SELF_INIT) {
                float di = dis[gr];
                float nrm = di * di;
                float4 s = {o.x * nrm, o.y * nrm, o.z * nrm, o.w * nrm};
                *(float4*)&Binit[(size_t)gr * 128 + tx * 4] = s;
            }
        }
    }
}

// one edge per 32 lanes, real edges only
__global__ __launch_bounds__(256)
void k_scatter(const float* __restrict__ H, const int* __restrict__ src,
               const int* __restrict__ dst, const float* __restrict__ dis,
               float* __restrict__ out, int E) {
    int e = blockIdx.x * 8 + (threadIdx.x >> 5);
    if (e >= E) return;
    int lane = threadIdx.x & 31;
    int s = src[e], d = dst[e];
    float nrm = dis[s] * dis[d];
    float4 v = *(const float4*)&H[(size_t)s * 128 + lane * 4];
    float* o = &out[(size_t)d * 128 + lane * 4];
    atomicAdd(o + 0, v.x * nrm);
    atomicAdd(o + 1, v.y * nrm);
    atomicAdd(o + 2, v.z * nrm);
    atomicAdd(o + 3, v.w * nrm);
}

// segment mean of relu(H + b); batch sorted ascending. one block per segment.
__global__ __launch_bounds__(128)
void k_pool(const float* __restrict__ H, const float* __restrict__ b,
            const int* __restrict__ batch, float* __restrict__ Z, int N) {
    int m = blockIdx.x;
    int lo = 0, hi = N;
    while (lo < hi) { int mid = (lo + hi) >> 1; if (batch[mid] < m) lo = mid + 1; else hi = mid; }
    int start = lo;
    hi = N;
    while (lo < hi) { int mid = (lo + hi) >> 1; if (batch[mid] < m + 1) lo = mid + 1; else hi = mid; }
    int end = lo;

    int j = threadIdx.x;
    float bj = b[j];
    float acc = 0.f;
    for (int i = start; i < end; ++i)
        acc += fmaxf(H[(size_t)i * 128 + j] + bj, 0.f);
    float cnt = (float)(end - start);
    Z[(size_t)m * 128 + j] = acc / fmaxf(cnt, 1.f);
}

extern "C" void kernel_launch(void* const* d_in, const int* in_sizes, int n_in,
                              void* d_out, int out_size, void* d_ws, size_t ws_size,
                              hipStream_t stream) {
    const float* x   = (const float*)d_in[0];
    const int*   ei  = (const int*)d_in[1];
    const int*   bat = (const int*)d_in[2];
    const float* W1  = (const float*)d_in[3];
    const float* b1  = (const float*)d_in[4];
    const float* W2  = (const float*)d_in[5];
    const float* b2  = (const float*)d_in[6];
    const float* Wf  = (const float*)d_in[7];
    const float* bf  = (const float*)d_in[8];
    float* out = (float*)d_out;

    const int N = in_sizes[0] / 128;
    const int E = in_sizes[1] / 2;
    const int M = out_size / 128;
    const int* src = ei;
    const int* dst = ei + E;

    char* ws = (char*)d_ws;
    const size_t feat_bytes = (size_t)N * 128 * sizeof(float);
    float* A   = (float*)ws;                          // [N,128]
    float* B   = (float*)(ws + feat_bytes);           // [N,128]
    float* dis = (float*)(ws + 2 * feat_bytes);       // [N]
    float* Z   = dis + N;                             // [M,128]

    const int gemm_blocks = (N + GEMM_ROWS - 1) / GEMM_ROWS;

    // 1. degrees -> dis
    hipMemsetAsync(dis, 0, (size_t)N * sizeof(float), stream);
    k_deg<<<(E + 255) / 256, 256, 0, stream>>>(dst, dis, E);
    k_dis<<<(N + 255) / 256, 256, 0, stream>>>(dis, N);

    // 2. A = x @ W1 ; B = dis^2 * A
    k_gemm128<false, false, true><<<gemm_blocks, 256, 0, stream>>>(
        x, W1, nullptr, nullptr, A, B, dis, N);

    // 3. B += scatter(A)
    k_scatter<<<(E + 7) / 8, 256, 0, stream>>>(A, src, dst, dis, B, E);

    // 4. A = relu(B + b1) @ W2 ; B = dis^2 * A
    k_gemm128<true, false, true><<<gemm_blocks, 256, 0, stream>>>(
        B, W2, b1, nullptr, A, B, dis, N);

    // 5. B += scatter(A)
    k_scatter<<<(E + 7) / 8, 256, 0, stream>>>(A, src, dst, dis, B, E);

    // 6. Z = segment-mean(relu(B + b2))
    k_pool<<<M, 128, 0, stream>>>(B, b2, bat, Z, N);

    // 7. out = Z @ Wf + bf
    k_gemm128<false, true, false><<<(M + GEMM_ROWS - 1) / GEMM_ROWS, 256, 0, stream>>>(
        Z, Wf, nullptr, bf, out, nullptr, nullptr, M);
}

// Round 8
// 581.114 us; speedup vs baseline: 3.0454x; 3.0454x over previous
//
#include <hip/hip_runtime.h>
#include <hip/hip_bf16.h>

// Pipeline (fp32):
//  1. counts[i] = #in-edges (int hist); dis[i] = rsqrt(counts+1)
//  2. CSR by dst: blocksum -> chunk scan -> scanwrite (rowStart, cursor) -> place (eidx)
//  3. A = x @ W1
//  4. B[d,:] = dis[d]^2*A[d,:] + sum_{e: dst=d} dis[src]*dis[d]*A[src,:]   (gather, no atomics)
//  5. A = relu(B + b1) @ W2
//  6. B = gather(A)
//  7. Z[m] = segment-mean relu(B + b2)  (batch sorted)
//  8. out = Z @ Wf + bf

#define GEMM_ROWS 32
#define CHUNK 1024   // elems per scan chunk (256 threads x 4)

__global__ __launch_bounds__(256)
void k_hist(const int* __restrict__ dst, int* __restrict__ counts, int E) {
    int i = blockIdx.x * 256 + threadIdx.x;
    if (i < E) atomicAdd(&counts[dst[i]], 1);
}

__global__ __launch_bounds__(256)
void k_dis(const int* __restrict__ counts, float* __restrict__ dis, int N) {
    int i = blockIdx.x * 256 + threadIdx.x;
    if (i < N) dis[i] = rsqrtf((float)counts[i] + 1.0f);   // +1 self loop
}

__global__ __launch_bounds__(256)
void k_blocksum(const int* __restrict__ counts, int* __restrict__ chunkSum, int N) {
    __shared__ int s[256];
    int b = blockIdx.x, t = threadIdx.x;
    int base = b * CHUNK + t * 4;
    int p = 0;
    #pragma unroll
    for (int i = 0; i < 4; ++i) if (base + i < N) p += counts[base + i];
    s[t] = p; __syncthreads();
    for (int off = 128; off > 0; off >>= 1) {
        if (t < off) s[t] += s[t + off];
        __syncthreads();
    }
    if (t == 0) chunkSum[b] = s[0];
}

// single block: exclusive scan of chunk sums (nChunks <= 256); also rowStart[N] = E
__global__ __launch_bounds__(256)
void k_scanchunks(const int* __restrict__ chunkSum, int* __restrict__ chunkOff,
                  int* __restrict__ rowStart, int nChunks, int N, int E) {
    __shared__ int s[256];
    int t = threadIdx.x;
    int v = (t < nChunks) ? chunkSum[t] : 0;
    s[t] = v; __syncthreads();
    for (int off = 1; off < 256; off <<= 1) {
        int u = (t >= off) ? s[t - off] : 0;
        __syncthreads();
        s[t] += u;
        __syncthreads();
    }
    if (t < nChunks) chunkOff[t] = s[t] - v;   // exclusive
    if (t == 0) rowStart[N] = E;
}

// NOTE: counts and cursor may ALIAS (each thread reads its 4 counts into
// registers before writing cursor at the same addresses) -> no __restrict__.
__global__ __launch_bounds__(256)
void k_scanwrite(const int* counts, const int* __restrict__ chunkOff,
                 int* __restrict__ rowStart, int* cursor, int N) {
    __shared__ int s[256];
    int b = blockIdx.x, t = threadIdx.x;
    int base = b * CHUNK + t * 4;
    int c[4]; int p = 0;
    #pragma unroll
    for (int i = 0; i < 4; ++i) { c[i] = (base + i < N) ? counts[base + i] : 0; p += c[i]; }
    s[t] = p; __syncthreads();
    for (int off = 1; off < 256; off <<= 1) {
        int u = (t >= off) ? s[t - off] : 0;
        __syncthreads();
        s[t] += u;
        __syncthreads();
    }
    int off = chunkOff[b] + s[t] - p;   // exclusive prefix for this thread
    #pragma unroll
    for (int i = 0; i < 4; ++i) {
        if (base + i < N) { rowStart[base + i] = off; cursor[base + i] = off; off += c[i]; }
    }
}

__global__ __launch_bounds__(256)
void k_place(const int* __restrict__ src, const int* __restrict__ dst,
             int* __restrict__ cursor, int* __restrict__ eidx, int E) {
    int e = blockIdx.x * 256 + threadIdx.x;
    if (e >= E) return;
    int d = dst[e];
    int pos = atomicAdd(&cursor[d], 1);
    eidx[pos] = src[e];
}

// one 64-lane wave per node; lane holds 2 floats (128 cols). No atomics.
__global__ __launch_bounds__(256)
void k_gather(const float* __restrict__ A, const float* __restrict__ dis,
              const int* __restrict__ rowStart, const int* __restrict__ eidx,
              float* __restrict__ B, int N) {
    int d = blockIdx.x * 4 + (threadIdx.x >> 6);
    if (d >= N) return;
    int lane = threadIdx.x & 63;
    float dd = dis[d];
    int beg = rowStart[d], end = rowStart[d + 1];
    float2 v = *(const float2*)&A[(size_t)d * 128 + lane * 2];
    float2 acc = { v.x * dd * dd, v.y * dd * dd };      // self loop
    for (int j = beg; j < end; ++j) {
        int s = eidx[j];                                 // wave-uniform
        float nrm = dd * dis[s];
        float2 u = *(const float2*)&A[(size_t)s * 128 + lane * 2];
        acc.x += nrm * u.x;
        acc.y += nrm * u.y;
    }
    *(float2*)&B[(size_t)d * 128 + lane * 2] = acc;
}

// Y[r,:] = act(X[r,:]) @ W (+ bout), act = relu(x + bin) if RELU_IN.
template<bool RELU_IN, bool OUT_BIAS>
__global__ __launch_bounds__(256)
void k_gemm128(const float* __restrict__ X, const float* __restrict__ W,
               const float* __restrict__ bin, const float* __restrict__ bout,
               float* __restrict__ Y, int nrows) {
    __shared__ float Ws[64 * 128];
    __shared__ float Xs[GEMM_ROWS * 128];
    const int tid = threadIdx.x;
    const int row0 = blockIdx.x * GEMM_ROWS;

    {
        float4* Xsv = (float4*)Xs;
        #pragma unroll
        for (int i = 0; i < 4; ++i) {
            int idx = tid + 256 * i;
            int r   = idx >> 5;
            int c4  = idx & 31;
            int gr  = row0 + r;
            float4 v = {0.f, 0.f, 0.f, 0.f};
            if (gr < nrows) v = *(const float4*)&X[(size_t)gr * 128 + c4 * 4];
            if (RELU_IN) {
                float4 b = *(const float4*)&bin[c4 * 4];
                v.x = fmaxf(v.x + b.x, 0.f);
                v.y = fmaxf(v.y + b.y, 0.f);
                v.z = fmaxf(v.z + b.z, 0.f);
                v.w = fmaxf(v.w + b.w, 0.f);
            }
            Xsv[idx] = v;
        }
    }

    const int tx = tid & 31;
    const int ty = tid >> 5;
    float4 acc[4];
    #pragma unroll
    for (int r = 0; r < 4; ++r) acc[r] = {0.f, 0.f, 0.f, 0.f};

    for (int kk = 0; kk < 128; kk += 64) {
        __syncthreads();
        const float4* Wv = (const float4*)(W + kk * 128);
        float4* Wsv = (float4*)Ws;
        #pragma unroll
        for (int i = 0; i < 8; ++i) Wsv[tid + 256 * i] = Wv[tid + 256 * i];
        __syncthreads();

        #pragma unroll 4
        for (int k = 0; k < 64; ++k) {
            float4 w = *(const float4*)&Ws[k * 128 + tx * 4];
            #pragma unroll
            for (int r = 0; r < 4; ++r) {
                float xv = Xs[(ty + 8 * r) * 128 + kk + k];
                acc[r].x += xv * w.x;
                acc[r].y += xv * w.y;
                acc[r].z += xv * w.z;
                acc[r].w += xv * w.w;
            }
        }
    }

    #pragma unroll
    for (int r = 0; r < 4; ++r) {
        int gr = row0 + ty + 8 * r;
        if (gr < nrows) {
            float4 o = acc[r];
            if (OUT_BIAS) {
                float4 b = *(const float4*)&bout[tx * 4];
                o.x += b.x; o.y += b.y; o.z += b.z; o.w += b.w;
            }
            *(float4*)&Y[(size_t)gr * 128 + tx * 4] = o;
        }
    }
}

// segment mean of relu(H + b); batch sorted ascending. one block per segment.
__global__ __launch_bounds__(128)
void k_pool(const float* __restrict__ H, const float* __restrict__ b,
            const int* __restrict__ batch, float* __restrict__ Z, int N) {
    int m = blockIdx.x;
    int lo = 0, hi = N;
    while (lo < hi) { int mid = (lo + hi) >> 1; if (batch[mid] < m) lo = mid + 1; else hi = mid; }
    int start = lo;
    hi = N;
    while (lo < hi) { int mid = (lo + hi) >> 1; if (batch[mid] < m + 1) lo = mid + 1; else hi = mid; }
    int end = lo;

    int j = threadIdx.x;
    float bj = b[j];
    float acc = 0.f;
    for (int i = start; i < end; ++i)
        acc += fmaxf(H[(size_t)i * 128 + j] + bj, 0.f);
    float cnt = (float)(end - start);
    Z[(size_t)m * 128 + j] = acc / fmaxf(cnt, 1.f);
}

extern "C" void kernel_launch(void* const* d_in, const int* in_sizes, int n_in,
                              void* d_out, int out_size, void* d_ws, size_t ws_size,
                              hipStream_t stream) {
    const float* x   = (const float*)d_in[0];
    const int*   ei  = (const int*)d_in[1];
    const int*   bat = (const int*)d_in[2];
    const float* W1  = (const float*)d_in[3];
    const float* b1  = (const float*)d_in[4];
    const float* W2  = (const float*)d_in[5];
    const float* b2  = (const float*)d_in[6];
    const float* Wf  = (const float*)d_in[7];
    const float* bf  = (const float*)d_in[8];
    float* out = (float*)d_out;

    const int N = in_sizes[0] / 128;
    const int E = in_sizes[1] / 2;
    const int M = out_size / 128;
    const int* src = ei;
    const int* dst = ei + E;

    // workspace layout (16B-aligned chunks)
    char* ws = (char*)d_ws;
    const size_t feat_bytes = (size_t)N * 128 * sizeof(float);
    size_t off = 0;
    float* A        = (float*)(ws + off); off += feat_bytes;
    float* B        = (float*)(ws + off); off += feat_bytes;
    float* dis      = (float*)(ws + off); off += ((size_t)N * 4 + 15) & ~15ull;
    int*   counts   = (int*)  (ws + off); off += ((size_t)N * 4 + 15) & ~15ull;   // reused as cursor
    int*   rowStart = (int*)  (ws + off); off += ((size_t)(N + 1) * 4 + 15) & ~15ull;
    int*   eidx     = (int*)  (ws + off); off += ((size_t)E * 4 + 15) & ~15ull;
    int*   chunkSum = (int*)  (ws + off); off += 256 * 4;
    int*   chunkOff = (int*)  (ws + off); off += 256 * 4;
    float* Z        = A;   // A is dead after the last gather; pool reads only B

    const int nChunks = (N + CHUNK - 1) / CHUNK;          // 196 for N=200k (<=256)
    const int gemm_blocks = (N + GEMM_ROWS - 1) / GEMM_ROWS;

    // 1. histogram + dis
    hipMemsetAsync(counts, 0, (size_t)N * sizeof(int), stream);
    k_hist<<<(E + 255) / 256, 256, 0, stream>>>(dst, counts, E);
    k_dis<<<(N + 255) / 256, 256, 0, stream>>>(counts, dis, N);

    // 2. CSR build (rowStart, cursor=counts alias, eidx)
    k_blocksum<<<nChunks, 256, 0, stream>>>(counts, chunkSum, N);
    k_scanchunks<<<1, 256, 0, stream>>>(chunkSum, chunkOff, rowStart, nChunks, N, E);
    k_scanwrite<<<nChunks, 256, 0, stream>>>(counts, chunkOff, rowStart, counts, N);
    k_place<<<(E + 255) / 256, 256, 0, stream>>>(src, dst, counts, eidx, E);

    // 3. A = x @ W1
    k_gemm128<false, false><<<gemm_blocks, 256, 0, stream>>>(x, W1, nullptr, nullptr, A, N);

    // 4. B = gather(A)
    k_gather<<<(N + 3) / 4, 256, 0, stream>>>(A, dis, rowStart, eidx, B, N);

    // 5. A = relu(B + b1) @ W2
    k_gemm128<true, false><<<gemm_blocks, 256, 0, stream>>>(B, W2, b1, nullptr, A, N);

    // 6. B = gather(A)
    k_gather<<<(N + 3) / 4, 256, 0, stream>>>(A, dis, rowStart, eidx, B, N);

    // 7. Z = segment-mean(relu(B + b2))
    k_pool<<<M, 128, 0, stream>>>(B, b2, bat, Z, N);

    // 8. out = Z @ Wf + bf
    k_gemm128<false, true><<<(M + GEMM_ROWS - 1) / GEMM_ROWS, 256, 0, stream>>>(
        Z, Wf, nullptr, bf, out, M);
}